// Round 11
// baseline (67.539 us; speedup 1.0000x reference)
//
#include <hip/hip_runtime.h>
#include <math.h>

typedef float f32x16 __attribute__((ext_vector_type(16)));
typedef float f32x4 __attribute__((ext_vector_type(4)));
typedef _Float16 f16x8 __attribute__((ext_vector_type(8)));

#define N_NODES 2048
#define WHT_STRIDE 2208   // f16 elements per padded whT row (4416 B: 64 distinct 256B offsets)

__device__ __forceinline__ float elu1(float v) { return v > 0.f ? v : expm1f(v); }

__device__ __forceinline__ unsigned enc_f(float x) {
    unsigned b = __float_as_uint(x);
    return (b & 0x80000000u) ? ~b : (b | 0x80000000u);
}
__device__ __forceinline__ float dec_f(unsigned u) {
    unsigned b = (u & 0x80000000u) ? (u ^ 0x80000000u) : ~u;
    return __uint_as_float(b);
}

// Stage 1: Wh = X@Ws -> whTp (fp16, d-major, padded rows) + s,t + per-batch max(t).
__global__ __launch_bounds__(256) void gat_stage1(
    const float* __restrict__ X, const float* __restrict__ Ws, const float* __restrict__ av,
    _Float16* __restrict__ whTp, float* __restrict__ sv, float* __restrict__ tvv,
    unsigned* __restrict__ tmaxU) {
    __shared__ float xls[64][66];
    __shared__ float wss[64][64];
    __shared__ float avs[128];
    int tid = threadIdx.x;
    int b = blockIdx.x >> 5;
    int j0 = (blockIdx.x & 31) * 64;
    const float* Xb = X + ((long)(b * N_NODES + j0)) * 64;
#pragma unroll
    for (int k = 0; k < 4; ++k) {
        int i4 = k * 256 + tid;
        float4 v = *reinterpret_cast<const float4*>(Xb + i4 * 4);
        int row = i4 >> 4, c = (i4 & 15) * 4;
        *reinterpret_cast<float2*>(&xls[row][c]) = make_float2(v.x, v.y);
        *reinterpret_cast<float2*>(&xls[row][c + 2]) = make_float2(v.z, v.w);
        *reinterpret_cast<float4*>(&wss[0][0] + i4 * 4) = *reinterpret_cast<const float4*>(Ws + i4 * 4);
    }
    if (tid < 128) avs[tid] = av[tid];
    __syncthreads();
    int row = tid >> 2;
    int dblk = (tid & 3) * 16;
    float acc[16];
#pragma unroll
    for (int k = 0; k < 16; ++k) acc[k] = 0.f;
#pragma unroll 8
    for (int f = 0; f < 64; ++f) {
        float xv = xls[row][f];
        const float4* wr = reinterpret_cast<const float4*>(&wss[f][dblk]);
        float4 w0 = wr[0], w1 = wr[1], w2 = wr[2], w3 = wr[3];
        acc[0]  += xv * w0.x; acc[1]  += xv * w0.y; acc[2]  += xv * w0.z; acc[3]  += xv * w0.w;
        acc[4]  += xv * w1.x; acc[5]  += xv * w1.y; acc[6]  += xv * w1.z; acc[7]  += xv * w1.w;
        acc[8]  += xv * w2.x; acc[9]  += xv * w2.y; acc[10] += xv * w2.z; acc[11] += xv * w2.w;
        acc[12] += xv * w3.x; acc[13] += xv * w3.y; acc[14] += xv * w3.z; acc[15] += xv * w3.w;
    }
    float sp = 0.f, tp = 0.f;
#pragma unroll
    for (int k = 0; k < 16; ++k) {
        int d = dblk + k;
        whTp[(long)(b * 64 + d) * WHT_STRIDE + j0 + row] = (_Float16)acc[k];
        sp += acc[k] * avs[d];
        tp += acc[k] * avs[64 + d];
    }
    sp += __shfl_xor(sp, 1, 64); sp += __shfl_xor(sp, 2, 64);
    tp += __shfl_xor(tp, 1, 64); tp += __shfl_xor(tp, 2, 64);
    if ((tid & 3) == 0) {
        sv[b * N_NODES + j0 + row] = sp;
        tvv[b * N_NODES + j0 + row] = tp;
    }
    float tw = tp;
#pragma unroll
    for (int off = 4; off < 64; off <<= 1) tw = fmaxf(tw, __shfl_xor(tw, off, 64));
    if ((tid & 63) == 0) atomicMax(tmaxU + b, enc_f(tw));
}

// Stage 2: WAVE-LOCAL fused masked-softmax attention. NO barriers, NO main-loop LDS.
// Each wave owns (b, 32-row i-tile, j-slice of N/JS). A-frag built in registers
// (lane: row=lane&31, kgroup=lane>>5); B-frags read direct from padded whT (L2).
// 3-set register rotation, 2-step prefetch lead. acc = 2 x f32x16 (d 0-31 / 32-63).
template<int JS, int LOG2JS, bool DIRECT>
__global__ __launch_bounds__(256, 2) void gat_stage2(
    const float* __restrict__ A, const _Float16* __restrict__ whTp,
    const float* __restrict__ sv, const float* __restrict__ tvv,
    const unsigned* __restrict__ tmaxU,
    float* __restrict__ numw, float* __restrict__ denw, float* __restrict__ H) {
    const int SL = N_NODES / JS;          // j-slice length
    const int NSTEP = SL / 16;            // MFMA k-steps
    int tid = threadIdx.x;
    int wid = tid >> 6, lane = tid & 63;
    int nb = gridDim.x;
    int bid = ((int)blockIdx.x & 7) * (nb >> 3) + ((int)blockIdx.x >> 3);  // XCD chunked
    int gw = bid * 4 + wid;
    int js = gw & (JS - 1);
    int rest = gw >> LOG2JS;
    int it = rest & 63;
    int b = rest >> 6;
    int i0 = it * 32;
    int rowA = lane & 31, kg = lane >> 5;

    float s_reg = sv[b * N_NODES + i0 + rowA];
    float Tb = dec_f(tmaxU[b]);
    float m0 = s_reg + Tb;
    float Ci = fmaxf(m0, 0.2f * m0) - 5.0f;   // exponents <= 5 -> fp16-safe
    float den = 0.f;

    const float* pA = A + ((long)(b * N_NODES + i0 + rowA)) * N_NODES + js * SL + kg * 8;
    const float* pT = tvv + b * N_NODES + js * SL + kg * 8;
    const _Float16* pB0 = whTp + (long)(b * 64 + rowA) * WHT_STRIDE + js * SL + kg * 8;
    const _Float16* pB1 = pB0 + 32 * WHT_STRIDE;

    f32x16 acc0, acc1;
#pragma unroll
    for (int r = 0; r < 16; ++r) { acc0[r] = 0.f; acc1[r] = 0.f; }

    // 3 register sets (A8 + T8 + 2xB f16x8 each)
    f32x4 aA0, aA1, tA0, tA1, aB0, aB1, tB0, tB1, aC0, aC1, tC0, tC1;
    f16x8 bA0, bA1, bB0, bB1, bC0, bC1;

    // prologue: sets A,B <- steps 0,1
    aA0 = *reinterpret_cast<const f32x4*>(pA);
    aA1 = *reinterpret_cast<const f32x4*>(pA + 4);
    tA0 = *reinterpret_cast<const f32x4*>(pT);
    tA1 = *reinterpret_cast<const f32x4*>(pT + 4);
    bA0 = *reinterpret_cast<const f16x8*>(pB0);
    bA1 = *reinterpret_cast<const f16x8*>(pB1);
    aB0 = *reinterpret_cast<const f32x4*>(pA + 16);
    aB1 = *reinterpret_cast<const f32x4*>(pA + 20);
    tB0 = *reinterpret_cast<const f32x4*>(pT + 16);
    tB1 = *reinterpret_cast<const f32x4*>(pT + 20);
    bB0 = *reinterpret_cast<const f16x8*>(pB0 + 16);
    bB1 = *reinterpret_cast<const f16x8*>(pB1 + 16);

#define EXP1(AV, TV, QD)                                                   \
    { float e_ = s_reg + (TV); e_ = fmaxf(e_, 0.2f * e_);                  \
      float p_ = (AV) * __expf(e_ - Ci);                                   \
      QD = (_Float16)p_; den += (float)QD; }

#define STEP(c, CA0, CA1, CT0, CT1, CB0, CB1, NA0, NA1, NT0, NT1, NB0, NB1) \
    {                                                                       \
        int cn = (c) + 2 < NSTEP ? (c) + 2 : NSTEP - 1;                     \
        NA0 = *reinterpret_cast<const f32x4*>(pA + cn * 16);                \
        NA1 = *reinterpret_cast<const f32x4*>(pA + cn * 16 + 4);            \
        NT0 = *reinterpret_cast<const f32x4*>(pT + cn * 16);                \
        NT1 = *reinterpret_cast<const f32x4*>(pT + cn * 16 + 4);            \
        NB0 = *reinterpret_cast<const f16x8*>(pB0 + cn * 16);               \
        NB1 = *reinterpret_cast<const f16x8*>(pB1 + cn * 16);               \
        _Float16 q0, q1, q2, q3, q4, q5, q6, q7;                            \
        EXP1(CA0.x, CT0.x, q0) EXP1(CA0.y, CT0.y, q1)                       \
        EXP1(CA0.z, CT0.z, q2) EXP1(CA0.w, CT0.w, q3)                       \
        EXP1(CA1.x, CT1.x, q4) EXP1(CA1.y, CT1.y, q5)                       \
        EXP1(CA1.z, CT1.z, q6) EXP1(CA1.w, CT1.w, q7)                       \
        f16x8 af = {q0, q1, q2, q3, q4, q5, q6, q7};                        \
        acc0 = __builtin_amdgcn_mfma_f32_32x32x16_f16(af, CB0, acc0, 0, 0, 0); \
        acc1 = __builtin_amdgcn_mfma_f32_32x32x16_f16(af, CB1, acc1, 0, 0, 0); \
    }

#pragma unroll 1
    for (int c = 0; c + 3 <= NSTEP; c += 3) {
        STEP(c,     aA0, aA1, tA0, tA1, bA0, bA1, aC0, aC1, tC0, tC1, bC0, bC1)
        STEP(c + 1, aB0, aB1, tB0, tB1, bB0, bB1, aA0, aA1, tA0, tA1, bA0, bA1)
        STEP(c + 2, aC0, aC1, tC0, tC1, bC0, bC1, aB0, aB1, tB0, tB1, bB0, bB1)
    }
    if (NSTEP % 3 == 2) {
        STEP(NSTEP - 2, aA0, aA1, tA0, tA1, bA0, bA1, aC0, aC1, tC0, tC1, bC0, bC1)
        STEP(NSTEP - 1, aB0, aB1, tB0, tB1, bB0, bB1, aA0, aA1, tA0, tA1, bA0, bA1)
    } else if (NSTEP % 3 == 1) {
        STEP(NSTEP - 1, aA0, aA1, tA0, tA1, bA0, bA1, aC0, aC1, tC0, tC1, bC0, bC1)
    }
#undef STEP
#undef EXP1

    // row denominator: lanes l and l+32 hold the two k-group partials of row l&31
    den += __shfl_xor(den, 32, 64);
    int col = lane & 31;

    if (DIRECT) {
        float dinv = 1.f / den;
#pragma unroll
        for (int r = 0; r < 16; ++r) {
            int row = (r & 3) + 8 * (r >> 2) + 4 * kg;
            float* Hrow = H + ((long)(b * N_NODES + i0 + row)) * 64 + col;
            Hrow[0]  = elu1(acc0[r] * dinv);
            Hrow[32] = elu1(acc1[r] * dinv);
        }
    } else {
#pragma unroll
        for (int r = 0; r < 16; ++r) {
            int row = (r & 3) + 8 * (r >> 2) + 4 * kg;
            long base = ((long)((js * 8 + b) * N_NODES + i0 + row)) * 64 + col;
            numw[base]      = acc0[r];
            numw[base + 32] = acc1[r];
        }
        if (lane < 32) denw[(js * 8 + b) * N_NODES + i0 + lane] = den;
    }
}

// Combine JS j-split partials: H = elu(sum(num)/sum(den))
template<int JS>
__global__ __launch_bounds__(256) void gat_combine(
    const float* __restrict__ numw, const float* __restrict__ denw, float* __restrict__ H) {
    int f4 = blockIdx.x * 256 + threadIdx.x;    // 262144 float4s
    long e0 = (long)f4 * 4;
    int row = f4 >> 4;
    float nx = 0.f, ny = 0.f, nz = 0.f, nw = 0.f, d = 0.f;
#pragma unroll
    for (int s = 0; s < JS; ++s) {
        float4 v = *reinterpret_cast<const float4*>(numw + (long)s * (8L * N_NODES * 64) + e0);
        nx += v.x; ny += v.y; nz += v.z; nw += v.w;
        d += denw[s * 8 * N_NODES + row];
    }
    float dinv = 1.f / d;
    f32x4 o;
    o.x = elu1(nx * dinv); o.y = elu1(ny * dinv);
    o.z = elu1(nz * dinv); o.w = elu1(nw * dinv);
    __builtin_nontemporal_store(o, reinterpret_cast<f32x4*>(H + e0));
}

extern "C" void kernel_launch(void* const* d_in, const int* in_sizes, int n_in,
                              void* d_out, int out_size, void* d_ws, size_t ws_size,
                              hipStream_t stream) {
    const float* A  = (const float*)d_in[0];   // [8,2048,2048]
    const float* X  = (const float*)d_in[1];   // [8,2048,64]
    const float* Ws = (const float*)d_in[2];   // [64,64]
    const float* av = (const float*)d_in[3];   // [128,1]
    float* H = (float*)d_out;                  // [8,2048,64]

    char* ws = (char*)d_ws;
    _Float16* whTp = (_Float16*)ws;                      // 8*64*2208*2 = 2,260,992 B
    float* sv = (float*)(ws + 0x240000);                 // 64 KiB
    float* tv = (float*)(ws + 0x250000);                 // 64 KiB
    unsigned* tmaxU = (unsigned*)(ws + 0x260000);        // 4 KiB
    float* denw = (float*)(ws + 0x261000);               // up to 4*64 KiB
    float* numw = (float*)(ws + 0x2B0000);               // JS * 4 MiB
    const size_t need4 = 0x2B0000 + 4L * 8 * N_NODES * 64 * 4;   // ~19.6 MB
    const size_t need2 = 0x2B0000 + 2L * 8 * N_NODES * 64 * 4;   // ~11.2 MB

    hipMemsetAsync(tmaxU, 0, 8 * sizeof(unsigned), stream);
    gat_stage1<<<256, 256, 0, stream>>>(X, Ws, av, whTp, sv, tv, tmaxU);
    if (ws_size >= need4) {
        gat_stage2<4, 2, false><<<512, 256, 0, stream>>>(A, whTp, sv, tv, tmaxU, numw, denw, H);
        gat_combine<4><<<1024, 256, 0, stream>>>(numw, denw, H);
    } else if (ws_size >= need2) {
        gat_stage2<2, 1, false><<<256, 256, 0, stream>>>(A, whTp, sv, tv, tmaxU, numw, denw, H);
        gat_combine<2><<<1024, 256, 0, stream>>>(numw, denw, H);
    } else {
        gat_stage2<1, 0, true><<<128, 256, 0, stream>>>(A, whTp, sv, tv, tmaxU, nullptr, nullptr, H);
    }
}